// Round 1
// baseline (443.670 us; speedup 1.0000x reference)
//
#include <hip/hip_runtime.h>
#include <hip/hip_bf16.h>

// StateSpaceMixer MI355X implementation.
// B=4 T=4096 D=1024 S=2048 K=4. All inputs fp32; internal GEMMs in bf16 MFMA
// (fp32 accumulate). Estimated output abs err ~1e-4 vs fp32 reference.
//
// Workspace layout (requires >= 172 MiB):
//   [0,64M)    mixed bf16 [16384][2048]   (reused as z fp32 [16384][1024] after conv)
//   [64M,128M) h     bf16 [16384][2048]
//   [128M,160M) xb   bf16 [16384][1024]
//   [160M,168M) W_inT bf16 [4096][1024]
//   [168M,172M) W_outT bf16 [1024][2048]

#define Bdim 4
#define Tdim 4096
#define Ddim 1024
#define Sdim 2048
#define Mdim (Bdim * Tdim)   // 16384
#define LN_EPS 1e-5f

typedef __bf16 bf16;
typedef __bf16 bf16x8 __attribute__((ext_vector_type(8)));
typedef float f32x4 __attribute__((ext_vector_type(4)));

__device__ __forceinline__ void gload_lds16(const bf16* g, bf16* l) {
  // async global->LDS, 16B per lane; LDS dest is wave-uniform base + lane*16
  __builtin_amdgcn_global_load_lds((const __attribute__((address_space(1))) void*)g,
                                   (__attribute__((address_space(3))) void*)l,
                                   16, 0, 0);
}

__device__ __forceinline__ f32x4 zero4() {
  f32x4 z; z[0] = 0.f; z[1] = 0.f; z[2] = 0.f; z[3] = 0.f; return z;
}

// ---------------- Pass 0a: cast x fp32 -> bf16 ----------------
__global__ __launch_bounds__(256) void k_cast_x(const float* __restrict__ x,
                                                bf16* __restrict__ xb) {
  int gid = blockIdx.x * 256 + threadIdx.x;   // grid sized exactly: M*D/8 threads
  const float4* p = (const float4*)x + (size_t)gid * 2;
  float4 a = p[0], b = p[1];
  bf16x8 o;
  o[0] = (bf16)a.x; o[1] = (bf16)a.y; o[2] = (bf16)a.z; o[3] = (bf16)a.w;
  o[4] = (bf16)b.x; o[5] = (bf16)b.y; o[6] = (bf16)b.z; o[7] = (bf16)b.w;
  ((bf16x8*)xb)[gid] = o;
}

// ---------------- Pass 0b: transpose + cast weights ----------------
// out[c][r] = (bf16) in[r][c];  in: [R][C] fp32 row-major, out: [C][R] bf16
__global__ __launch_bounds__(256) void k_transpose_cast(const float* __restrict__ in,
                                                        bf16* __restrict__ out,
                                                        int R, int C) {
  __shared__ float tile[32][33];
  int tx = threadIdx.x & 31;
  int ty = threadIdx.x >> 5;           // 0..7
  int r0 = blockIdx.y * 32;
  int c0 = blockIdx.x * 32;
#pragma unroll
  for (int i = 0; i < 4; ++i)
    tile[ty + i * 8][tx] = in[(size_t)(r0 + ty + i * 8) * C + c0 + tx];
  __syncthreads();
#pragma unroll
  for (int i = 0; i < 4; ++i)
    out[(size_t)(c0 + ty + i * 8) * R + r0 + tx] = (bf16)tile[tx][ty + i * 8];
}

// ---------------- Pass 1: GEMM1 + bias + SiLU gating ----------------
// xb [M][1024] bf16, wt = W_inT [4096][1024] bf16.
// mixed[m][n] = (proj[m][n] + b_in[n]) * sigmoid(proj[m][n+2048] + b_in[n+2048])
__global__ __launch_bounds__(256, 2)
void k_gemm1_gate(const bf16* __restrict__ xb, const bf16* __restrict__ wt,
                  const float* __restrict__ b_in, bf16* __restrict__ mixed) {
  __shared__ bf16 Als[128 * 32];
  __shared__ bf16 Bml[128 * 32];
  __shared__ bf16 Bgl[128 * 32];

  const int tid = threadIdx.x;
  const int wave = tid >> 6;
  const int lane = tid & 63;
  const int lr = lane & 15;
  const int lk = lane >> 4;
  const int wr = wave >> 1, wc = wave & 1;

  const int m0 = blockIdx.y * 128;
  const int n0 = blockIdx.x * 128;

  const int srow = lane >> 2;          // 0..15
  const int skoff = (lane & 3) * 8;    // 0,8,16,24

  f32x4 accm[4][4], accg[4][4];
#pragma unroll
  for (int i = 0; i < 4; ++i)
#pragma unroll
    for (int j = 0; j < 4; ++j) { accm[i][j] = zero4(); accg[i][j] = zero4(); }

  const bf16* Ag = xb + (size_t)m0 * Ddim;
  const bf16* Bmg = wt + (size_t)n0 * Ddim;
  const bf16* Bgg = wt + (size_t)(Sdim + n0) * Ddim;

  for (int k0 = 0; k0 < Ddim; k0 += 32) {
    __syncthreads();  // prior compute done before LDS overwrite
#pragma unroll
    for (int j = 0; j < 2; ++j) {
      int row = j * 64 + wave * 16 + srow;
      size_t goff = (size_t)row * Ddim + k0 + skoff;
      int lbase = (j * 64 + wave * 16) * 32;   // wave-uniform LDS base (elems)
      gload_lds16(Ag + goff, &Als[lbase]);
      gload_lds16(Bmg + goff, &Bml[lbase]);
      gload_lds16(Bgg + goff, &Bgl[lbase]);
    }
    __syncthreads();  // vmcnt(0) drained by barrier: tiles ready

    bf16x8 af[4], bmf[4], bgf[4];
#pragma unroll
    for (int mi = 0; mi < 4; ++mi)
      af[mi] = *(const bf16x8*)&Als[(wr * 64 + mi * 16 + lr) * 32 + lk * 8];
#pragma unroll
    for (int ni = 0; ni < 4; ++ni) {
      bmf[ni] = *(const bf16x8*)&Bml[(wc * 64 + ni * 16 + lr) * 32 + lk * 8];
      bgf[ni] = *(const bf16x8*)&Bgl[(wc * 64 + ni * 16 + lr) * 32 + lk * 8];
    }
#pragma unroll
    for (int mi = 0; mi < 4; ++mi)
#pragma unroll
      for (int ni = 0; ni < 4; ++ni) {
        accm[mi][ni] = __builtin_amdgcn_mfma_f32_16x16x32_bf16(af[mi], bmf[ni], accm[mi][ni], 0, 0, 0);
        accg[mi][ni] = __builtin_amdgcn_mfma_f32_16x16x32_bf16(af[mi], bgf[ni], accg[mi][ni], 0, 0, 0);
      }
  }

  // epilogue: C/D layout col=lane&15, row=(lane>>4)*4+i  [m89/m91 verified]
#pragma unroll
  for (int mi = 0; mi < 4; ++mi)
#pragma unroll
    for (int ni = 0; ni < 4; ++ni)
#pragma unroll
      for (int i = 0; i < 4; ++i) {
        int row = m0 + wr * 64 + mi * 16 + lk * 4 + i;
        int col = n0 + wc * 64 + ni * 16 + lr;
        float pm = accm[mi][ni][i] + b_in[col];
        float pg = accg[mi][ni][i] + b_in[col + Sdim];
        float v = pm / (1.0f + __expf(-pg));
        mixed[(size_t)row * Sdim + col] = (bf16)v;
      }
}

// ---------------- Pass 2: depthwise causal conv K=4 ----------------
// h[b,t,s] = cb[s] + sum_k cw[s][k] * mixed[b, t+k-3, s]   (zero for t+k-3<0)
__global__ __launch_bounds__(256) void k_conv(const bf16* __restrict__ mixed,
                                              const float* __restrict__ cw,
                                              const float* __restrict__ cb,
                                              bf16* __restrict__ h) {
  int gid = blockIdx.x * 256 + threadIdx.x;  // 4*512*256 = 524288 threads
  int cg = gid & 255;            // channel group (8 ch)
  int tg = (gid >> 8) & 511;     // t group (8 t)
  int b = gid >> 17;
  int ch0 = cg * 8;
  int t0 = tg * 8;
  const size_t base = ((size_t)b * Tdim) * Sdim + ch0;

  float4 w4[8];
  float bias[8];
#pragma unroll
  for (int j = 0; j < 8; ++j) {
    w4[j] = ((const float4*)cw)[ch0 + j];   // conv_w row = exactly 4 floats
    bias[j] = cb[ch0 + j];
  }

  bf16x8 zv;
#pragma unroll
  for (int j = 0; j < 8; ++j) zv[j] = (bf16)0.0f;

  bf16x8 win[11];  // rows t0-3 .. t0+7
#pragma unroll
  for (int i = 0; i < 11; ++i) {
    int t = t0 - 3 + i;
    win[i] = (t >= 0) ? *(const bf16x8*)(mixed + base + (size_t)t * Sdim) : zv;
  }

#pragma unroll
  for (int i = 0; i < 8; ++i) {
    bf16x8 o;
#pragma unroll
    for (int j = 0; j < 8; ++j) {
      float a = bias[j]
              + w4[j].x * (float)win[i + 0][j]
              + w4[j].y * (float)win[i + 1][j]
              + w4[j].z * (float)win[i + 2][j]
              + w4[j].w * (float)win[i + 3][j];
      o[j] = (bf16)a;
    }
    *(bf16x8*)(h + base + (size_t)(t0 + i) * Sdim) = o;
  }
}

// ---------------- Pass 3: GEMM2 + bias + residual ----------------
// h [M][2048] bf16, wt = W_outT [1024][2048] bf16.
// z[m][n] = x[m][n] + b_out[n] + sum_s h[m][s]*W_out[s][n]   (fp32)
__global__ __launch_bounds__(256, 2)
void k_gemm2_res(const bf16* __restrict__ h, const bf16* __restrict__ wt,
                 const float* __restrict__ b_out, const float* __restrict__ x,
                 float* __restrict__ z) {
  __shared__ bf16 Als[128 * 32];
  __shared__ bf16 Bls[128 * 32];

  const int tid = threadIdx.x;
  const int wave = tid >> 6;
  const int lane = tid & 63;
  const int lr = lane & 15;
  const int lk = lane >> 4;
  const int wr = wave >> 1, wc = wave & 1;

  const int m0 = blockIdx.y * 128;
  const int n0 = blockIdx.x * 128;

  const int srow = lane >> 2;
  const int skoff = (lane & 3) * 8;

  f32x4 acc[4][4];
#pragma unroll
  for (int i = 0; i < 4; ++i)
#pragma unroll
    for (int j = 0; j < 4; ++j) acc[i][j] = zero4();

  const bf16* Ag = h + (size_t)m0 * Sdim;
  const bf16* Bg = wt + (size_t)n0 * Sdim;

  for (int k0 = 0; k0 < Sdim; k0 += 32) {
    __syncthreads();
#pragma unroll
    for (int j = 0; j < 2; ++j) {
      int row = j * 64 + wave * 16 + srow;
      size_t goff = (size_t)row * Sdim + k0 + skoff;
      int lbase = (j * 64 + wave * 16) * 32;
      gload_lds16(Ag + goff, &Als[lbase]);
      gload_lds16(Bg + goff, &Bls[lbase]);
    }
    __syncthreads();

    bf16x8 af[4], bf[4];
#pragma unroll
    for (int mi = 0; mi < 4; ++mi)
      af[mi] = *(const bf16x8*)&Als[(wr * 64 + mi * 16 + lr) * 32 + lk * 8];
#pragma unroll
    for (int ni = 0; ni < 4; ++ni)
      bf[ni] = *(const bf16x8*)&Bls[(wc * 64 + ni * 16 + lr) * 32 + lk * 8];
#pragma unroll
    for (int mi = 0; mi < 4; ++mi)
#pragma unroll
      for (int ni = 0; ni < 4; ++ni)
        acc[mi][ni] = __builtin_amdgcn_mfma_f32_16x16x32_bf16(af[mi], bf[ni], acc[mi][ni], 0, 0, 0);
  }

#pragma unroll
  for (int mi = 0; mi < 4; ++mi)
#pragma unroll
    for (int ni = 0; ni < 4; ++ni)
#pragma unroll
      for (int i = 0; i < 4; ++i) {
        int row = m0 + wr * 64 + mi * 16 + lk * 4 + i;
        int col = n0 + wc * 64 + ni * 16 + lr;
        size_t idx = (size_t)row * Ddim + col;
        z[idx] = x[idx] + b_out[col] + acc[mi][ni][i];
      }
}

// ---------------- Pass 4: LayerNorm over D=1024 ----------------
__global__ __launch_bounds__(256) void k_ln(const float* __restrict__ z,
                                            const float* __restrict__ gamma,
                                            const float* __restrict__ beta,
                                            float* __restrict__ out) {
  int row = blockIdx.x;
  int tid = threadIdx.x;
  const float4* zr = (const float4*)(z + (size_t)row * Ddim);
  float4 v = zr[tid];
  float s = v.x + v.y + v.z + v.w;
  float ss = v.x * v.x + v.y * v.y + v.z * v.z + v.w * v.w;
#pragma unroll
  for (int off = 32; off > 0; off >>= 1) {
    s += __shfl_xor(s, off);
    ss += __shfl_xor(ss, off);
  }
  __shared__ float ps[4], pss[4];
  int wave = tid >> 6, lane = tid & 63;
  if (lane == 0) { ps[wave] = s; pss[wave] = ss; }
  __syncthreads();
  float tots = ps[0] + ps[1] + ps[2] + ps[3];
  float totss = pss[0] + pss[1] + pss[2] + pss[3];
  float mu = tots * (1.0f / (float)Ddim);
  float var = totss * (1.0f / (float)Ddim) - mu * mu;
  float rs = rsqrtf(var + LN_EPS);
  float4 gg = ((const float4*)gamma)[tid];
  float4 bb = ((const float4*)beta)[tid];
  float4 o;
  o.x = (v.x - mu) * rs * gg.x + bb.x;
  o.y = (v.y - mu) * rs * gg.y + bb.y;
  o.z = (v.z - mu) * rs * gg.z + bb.z;
  o.w = (v.w - mu) * rs * gg.w + bb.w;
  ((float4*)(out + (size_t)row * Ddim))[tid] = o;
}

// ---------------- launch ----------------
extern "C" void kernel_launch(void* const* d_in, const int* in_sizes, int n_in,
                              void* d_out, int out_size, void* d_ws, size_t ws_size,
                              hipStream_t stream) {
  const float* x = (const float*)d_in[0];
  const float* W_in = (const float*)d_in[1];
  const float* b_in = (const float*)d_in[2];
  const float* conv_w = (const float*)d_in[3];
  const float* conv_b = (const float*)d_in[4];
  const float* W_out = (const float*)d_in[5];
  const float* b_out = (const float*)d_in[6];
  const float* gamma = (const float*)d_in[7];
  const float* beta = (const float*)d_in[8];
  float* out = (float*)d_out;

  char* ws = (char*)d_ws;
  bf16* mixed = (bf16*)ws;                              // 64 MiB
  bf16* hbuf = (bf16*)(ws + ((size_t)64 << 20));        // 64 MiB
  bf16* xb = (bf16*)(ws + ((size_t)128 << 20));         // 32 MiB
  bf16* winT = (bf16*)(ws + ((size_t)160 << 20));       // 8 MiB
  bf16* woutT = (bf16*)(ws + ((size_t)168 << 20));      // 4 MiB
  float* z = (float*)mixed;  // mixed dead after conv; z fp32 [M][D] = 64 MiB

  // Pass 0: casts / transposes
  k_cast_x<<<dim3(Mdim * Ddim / 8 / 256), dim3(256), 0, stream>>>(x, xb);
  k_transpose_cast<<<dim3(4096 / 32, 1024 / 32), dim3(256), 0, stream>>>(W_in, winT, 1024, 4096);
  k_transpose_cast<<<dim3(1024 / 32, 2048 / 32), dim3(256), 0, stream>>>(W_out, woutT, 2048, 1024);
  // Pass 1: GEMM1 + gating (grid.x = n-tiles so consecutive blocks share A rows in L2)
  k_gemm1_gate<<<dim3(Sdim / 128, Mdim / 128), dim3(256), 0, stream>>>(xb, winT, b_in, mixed);
  // Pass 2: depthwise causal conv
  k_conv<<<dim3(Bdim * (Tdim / 8) * (Sdim / 8) / 256), dim3(256), 0, stream>>>(mixed, conv_w, conv_b, hbuf);
  // Pass 3: GEMM2 + bias + residual
  k_gemm2_res<<<dim3(Ddim / 128, Mdim / 128), dim3(256), 0, stream>>>(hbuf, woutT, b_out, x, z);
  // Pass 4: LayerNorm
  k_ln<<<dim3(Mdim), dim3(256), 0, stream>>>(z, gamma, beta, out);
}